// Round 1
// baseline (554.421 us; speedup 1.0000x reference)
//
#include <hip/hip_runtime.h>

#define F_IN 128
#define F_OUT 32

// ---------------- K0: spectral norm, write W/sigma to ws ----------------
// sigma = ||W v|| where v = normalize(W^T u). One block, 128 threads.
__global__ void k0_specnorm(const float* __restrict__ W, const float* __restrict__ u,
                            float* __restrict__ Wsc) {
    __shared__ float v[F_IN];
    __shared__ float red[F_IN];
    __shared__ float scal;
    int t = threadIdx.x;  // 0..127
    // v_j = sum_i W[i][j] * u[i]
    float acc = 0.f;
    for (int i = 0; i < F_OUT; ++i) acc += W[i * F_IN + t] * u[i];
    v[t] = acc;
    red[t] = acc * acc;
    __syncthreads();
    if (t == 0) {
        float s = 0.f;
        for (int i = 0; i < F_IN; ++i) s += red[i];
        scal = 1.0f / fmaxf(sqrtf(s), 1e-12f);
    }
    __syncthreads();
    v[t] = v[t] * scal;   // own-element update, safe
    __syncthreads();
    // (Wv)_i for i < 32, then sigma = ||Wv||
    if (t < F_OUT) {
        float a2 = 0.f;
        for (int j = 0; j < F_IN; ++j) a2 += W[t * F_IN + j] * v[j];
        red[t] = a2 * a2;
    }
    __syncthreads();
    if (t == 0) {
        float s = 0.f;
        for (int i = 0; i < F_OUT; ++i) s += red[i];
        scal = 1.0f / fmaxf(sqrtf(s), 1e-30f);  // 1/sigma
    }
    __syncthreads();
    float is = scal;
    for (int i = 0; i < F_OUT; ++i)
        Wsc[i * F_IN + t] = W[i * F_IN + t] * is;
}

// ---------------- K1: xw = x @ Wsc^T  [N,32] ----------------
__global__ void k1_xw(const float* __restrict__ x, const float* __restrict__ Wsc,
                      float* __restrict__ xw, int Nn) {
    int id = blockIdx.x * blockDim.x + threadIdx.x;
    if (id >= Nn * F_OUT) return;
    int r = id >> 5, f = id & 31;
    const float4* x4 = (const float4*)(x + (size_t)r * F_IN);
    const float4* w4 = (const float4*)(Wsc + (size_t)f * F_IN);
    float acc = 0.f;
#pragma unroll
    for (int k = 0; k < F_IN / 4; ++k) {
        float4 a = x4[k];
        float4 b = w4[k];
        acc += a.x * b.x + a.y * b.y + a.z * b.z + a.w * b.w;
    }
    xw[id] = acc;
}

// ---------------- K2: degree count over col ----------------
__global__ void k2_deg(const int* __restrict__ col, int* __restrict__ cnt, int E_) {
    int e = blockIdx.x * blockDim.x + threadIdx.x;
    if (e < E_) atomicAdd(&cnt[col[e]], 1);
}

// ---------------- K3: dis = rsqrt(deg + 1)  (self loop => deg>0 always) ----
__global__ void k3_dis(const int* __restrict__ cnt, float* __restrict__ dis, int Nn) {
    int i = blockIdx.x * blockDim.x + threadIdx.x;
    if (i < Nn) {
        float d = (float)cnt[i] + 1.0f;
        dis[i] = rsqrtf(d);
    }
}

// ---------------- K4: edge scatter: out[col] += xw[row]*dis[row]*dis[col] ----
__global__ void k4_scatter(const int* __restrict__ ei, const float* __restrict__ xw,
                           const float* __restrict__ dis, float* __restrict__ out, int E_) {
    int id = blockIdx.x * blockDim.x + threadIdx.x;
    if (id >= E_ * F_OUT) return;  // E*32 = 51.2M < 2^31
    int e = id >> 5, f = id & 31;
    int r = ei[e];
    int c = ei[E_ + e];
    float nrm = dis[r] * dis[c];
    atomicAdd(&out[(size_t)c * F_OUT + f], xw[(size_t)r * F_OUT + f] * nrm);
}

// ---------------- K5: epilogue: + self-loop + bias, PReLU ----------------
__global__ void k5_epi(const float* __restrict__ xw, const float* __restrict__ dis,
                       const float* __restrict__ bias, const float* __restrict__ pa,
                       float* __restrict__ out, int Nn) {
    int id = blockIdx.x * blockDim.x + threadIdx.x;
    if (id >= Nn * F_OUT) return;
    int i = id >> 5, f = id & 31;
    float d = dis[i];
    float v = out[id] + xw[id] * d * d + bias[f];
    float a = pa[0];
    out[id] = (v >= 0.f) ? v : a * v;
}

extern "C" void kernel_launch(void* const* d_in, const int* in_sizes, int n_in,
                              void* d_out, int out_size, void* d_ws, size_t ws_size,
                              hipStream_t stream) {
    const float* x    = (const float*)d_in[0];
    const int*   ei   = (const int*)d_in[1];   // [2, E] flat: row = ei[0:E], col = ei[E:2E]
    const float* W    = (const float*)d_in[2];
    const float* bias = (const float*)d_in[3];
    const float* pa   = (const float*)d_in[4];
    const float* u    = (const float*)d_in[5];

    int Nn = in_sizes[0] / F_IN;   // 100000
    int E_ = in_sizes[1] / 2;      // 1600000
    float* out = (float*)d_out;

    // ws layout: xw [N*32] | Wsc [32*128] | dis/cnt [N]
    float* xw  = (float*)d_ws;
    float* Wsc = xw + (size_t)Nn * F_OUT;
    float* dis = Wsc + (size_t)F_OUT * F_IN;
    int*   cnt = (int*)dis;

    hipMemsetAsync(cnt, 0, (size_t)Nn * sizeof(int), stream);
    hipMemsetAsync(d_out, 0, (size_t)Nn * F_OUT * sizeof(float), stream);

    k0_specnorm<<<1, 128, 0, stream>>>(W, u, Wsc);

    int nThreads1 = Nn * F_OUT;
    k1_xw<<<(nThreads1 + 255) / 256, 256, 0, stream>>>(x, Wsc, xw, Nn);

    k2_deg<<<(E_ + 255) / 256, 256, 0, stream>>>(ei + E_, cnt, E_);

    k3_dis<<<(Nn + 255) / 256, 256, 0, stream>>>(cnt, dis, Nn);

    int nThreads4 = E_ * F_OUT;
    k4_scatter<<<(nThreads4 + 255) / 256, 256, 0, stream>>>(ei, xw, dis, out, E_);

    k5_epi<<<(nThreads1 + 255) / 256, 256, 0, stream>>>(xw, dis, bias, pa, out, Nn);
}

// Round 2
// 408.040 us; speedup vs baseline: 1.3587x; 1.3587x over previous
//
#include <hip/hip_runtime.h>

#define F_IN 128
#define F_OUT 32

// ---------------- K0: spectral norm, write W/sigma to ws ----------------
__global__ void k0_specnorm(const float* __restrict__ W, const float* __restrict__ u,
                            float* __restrict__ Wsc) {
    __shared__ float v[F_IN];
    __shared__ float red[F_IN];
    __shared__ float scal;
    int t = threadIdx.x;  // 0..127
    float acc = 0.f;
    for (int i = 0; i < F_OUT; ++i) acc += W[i * F_IN + t] * u[i];
    v[t] = acc;
    red[t] = acc * acc;
    __syncthreads();
    if (t == 0) {
        float s = 0.f;
        for (int i = 0; i < F_IN; ++i) s += red[i];
        scal = 1.0f / fmaxf(sqrtf(s), 1e-12f);
    }
    __syncthreads();
    v[t] = v[t] * scal;
    __syncthreads();
    if (t < F_OUT) {
        float a2 = 0.f;
        for (int j = 0; j < F_IN; ++j) a2 += W[t * F_IN + j] * v[j];
        red[t] = a2 * a2;
    }
    __syncthreads();
    if (t == 0) {
        float s = 0.f;
        for (int i = 0; i < F_OUT; ++i) s += red[i];
        scal = 1.0f / fmaxf(sqrtf(s), 1e-30f);  // 1/sigma
    }
    __syncthreads();
    float is = scal;
    for (int i = 0; i < F_OUT; ++i)
        Wsc[i * F_IN + t] = W[i * F_IN + t] * is;
}

// ---------------- K1: xw = x @ Wsc^T, LDS-tiled, 4x4 micro-tile ----------
// Block: 256 threads, 128 rows x 32 feats. LDS: xs[128][65] (k-chunked by 64),
// wt[128][32] transposed W (k-major). All compute-phase LDS reads conflict-free.
__global__ __launch_bounds__(256) void k1_xw(const float* __restrict__ x,
                                             const float* __restrict__ Wsc,
                                             float* __restrict__ xw, int Nn) {
    __shared__ float xs[128 * 65];   // [r][kk], stride 65
    __shared__ float wt[128 * 32];   // [k][f], stride 32
    int t = threadIdx.x;
    int rbase = blockIdx.x * 128;

    // stage W transposed: thread t -> W row f = t>>3, k-range 16*(t&7)..+15
    {
        int f = t >> 3;
        int kb = 16 * (t & 7);
        const float4* wrow = (const float4*)(Wsc + (size_t)f * F_IN + kb);
#pragma unroll
        for (int j = 0; j < 4; ++j) {
            float4 w = wrow[j];
            int k = kb + 4 * j;
            wt[(k + 0) * 32 + f] = w.x;
            wt[(k + 1) * 32 + f] = w.y;
            wt[(k + 2) * 32 + f] = w.z;
            wt[(k + 3) * 32 + f] = w.w;
        }
    }

    int r0 = (t >> 3) * 4;   // 0..124
    int f0 = (t & 7) * 4;    // 0..28
    float4 acc0 = {0, 0, 0, 0}, acc1 = {0, 0, 0, 0};
    float4 acc2 = {0, 0, 0, 0}, acc3 = {0, 0, 0, 0};

    const float4* wt4 = (const float4*)wt;
    int fq = f0 >> 2;

    for (int kc = 0; kc < 2; ++kc) {
        __syncthreads();  // wt ready (1st iter) / xs no longer read (2nd iter)
        // stage x chunk: 128 rows x 64 cols
        {
            int rr = t >> 4;          // 0..15
            int k0 = 4 * (t & 15);    // 0..60
#pragma unroll
            for (int p = 0; p < 8; ++p) {
                int r = p * 16 + rr;
                int grow = rbase + r;
                if (grow >= Nn) grow = Nn - 1;
                float4 v = *(const float4*)(x + (size_t)grow * F_IN + kc * 64 + k0);
                xs[r * 65 + k0 + 0] = v.x;
                xs[r * 65 + k0 + 1] = v.y;
                xs[r * 65 + k0 + 2] = v.z;
                xs[r * 65 + k0 + 3] = v.w;
            }
        }
        __syncthreads();
#pragma unroll 4
        for (int kk = 0; kk < 64; ++kk) {
            int k = kc * 64 + kk;
            float4 w = wt4[k * 8 + fq];
            float x0 = xs[(r0 + 0) * 65 + kk];
            float x1 = xs[(r0 + 1) * 65 + kk];
            float x2 = xs[(r0 + 2) * 65 + kk];
            float x3 = xs[(r0 + 3) * 65 + kk];
            acc0.x += x0 * w.x; acc0.y += x0 * w.y; acc0.z += x0 * w.z; acc0.w += x0 * w.w;
            acc1.x += x1 * w.x; acc1.y += x1 * w.y; acc1.z += x1 * w.z; acc1.w += x1 * w.w;
            acc2.x += x2 * w.x; acc2.y += x2 * w.y; acc2.z += x2 * w.z; acc2.w += x2 * w.w;
            acc3.x += x3 * w.x; acc3.y += x3 * w.y; acc3.z += x3 * w.z; acc3.w += x3 * w.w;
        }
    }
    int g0 = rbase + r0;
    if (g0 + 0 < Nn) *(float4*)(xw + (size_t)(g0 + 0) * F_OUT + f0) = acc0;
    if (g0 + 1 < Nn) *(float4*)(xw + (size_t)(g0 + 1) * F_OUT + f0) = acc1;
    if (g0 + 2 < Nn) *(float4*)(xw + (size_t)(g0 + 2) * F_OUT + f0) = acc2;
    if (g0 + 3 < Nn) *(float4*)(xw + (size_t)(g0 + 3) * F_OUT + f0) = acc3;
}

// ---------------- K2: degree count over col ----------------
__global__ void k2_deg(const int* __restrict__ col, int* __restrict__ cnt, int E_) {
    int e = blockIdx.x * blockDim.x + threadIdx.x;
    if (e < E_) atomicAdd(&cnt[col[e]], 1);
}

// ---------------- K3: dis = rsqrt(deg + 1) ----------------
__global__ void k3_dis(const int* __restrict__ cnt, float* __restrict__ dis, int Nn) {
    int i = blockIdx.x * blockDim.x + threadIdx.x;
    if (i < Nn) dis[i] = rsqrtf((float)cnt[i] + 1.0f);
}

// ---------------- Scan: 3-kernel exclusive prefix sum of cnt -> cursor ----
// blocks of 1024 elements (256 threads x 4)
__global__ void k_s1(const int* __restrict__ cnt, int* __restrict__ bsum, int Nn) {
    __shared__ int sd[256];
    int t = threadIdx.x;
    int base = blockIdx.x * 1024 + 4 * t;
    int s = 0;
#pragma unroll
    for (int i = 0; i < 4; ++i) {
        int idx = base + i;
        s += (idx < Nn) ? cnt[idx] : 0;
    }
    sd[t] = s;
    __syncthreads();
    for (int o = 128; o > 0; o >>= 1) {
        if (t < o) sd[t] += sd[t + o];
        __syncthreads();
    }
    if (t == 0) bsum[blockIdx.x] = sd[0];
}

__global__ void k_s2(int* __restrict__ bsum, int nb) {
    if (threadIdx.x == 0 && blockIdx.x == 0) {
        int run = 0;
        for (int i = 0; i < nb; ++i) { int v = bsum[i]; bsum[i] = run; run += v; }
    }
}

__global__ void k_s3(const int* __restrict__ cnt, const int* __restrict__ boff,
                     int* __restrict__ cursor, int Nn) {
    __shared__ int sd[256];
    int t = threadIdx.x;
    int base = blockIdx.x * 1024 + 4 * t;
    int loc[4];
    int s = 0;
#pragma unroll
    for (int i = 0; i < 4; ++i) {
        int idx = base + i;
        loc[i] = (idx < Nn) ? cnt[idx] : 0;
        s += loc[i];
    }
    int tsum = s;
    sd[t] = tsum;
    __syncthreads();
    // Hillis-Steele inclusive scan over 256 thread sums
    for (int o = 1; o < 256; o <<= 1) {
        int v = (t >= o) ? sd[t - o] : 0;
        __syncthreads();
        sd[t] += v;
        __syncthreads();
    }
    int excl = sd[t] - tsum + boff[blockIdx.x];
#pragma unroll
    for (int i = 0; i < 4; ++i) {
        int idx = base + i;
        if (idx < Nn) cursor[idx] = excl;
        excl += loc[i];
    }
}

// ---------------- kSort: bucket edges by col (counting sort) --------------
__global__ void k_sort(const int* __restrict__ ei, int* __restrict__ cursor,
                       int* __restrict__ esr, int E_) {
    int e = blockIdx.x * blockDim.x + threadIdx.x;
    if (e < E_) {
        int c = ei[E_ + e];
        int p = atomicAdd(&cursor[c], 1);
        esr[p] = ei[e];   // row
    }
}

// ---------------- K4g: per-node gather + epilogue (no fp32 atomics) -------
// 32 lanes per node (one per feature). cursor[c] = segment END after sort.
__global__ void k4_gather(const int* __restrict__ esr, const int* __restrict__ endp,
                          const int* __restrict__ deg, const float* __restrict__ xw,
                          const float* __restrict__ dis, const float* __restrict__ bias,
                          const float* __restrict__ pa, float* __restrict__ out, int Nn) {
    int t = threadIdx.x;
    int c = blockIdx.x * 8 + (t >> 5);
    if (c >= Nn) return;
    int f = t & 31;
    int end = endp[c];
    int start = end - deg[c];
    float dc = dis[c];
    float acc = 0.f;
    for (int j = start; j < end; ++j) {
        int r = esr[j];
        acc += xw[(size_t)r * F_OUT + f] * dis[r];
    }
    float v = acc * dc + xw[(size_t)c * F_OUT + f] * dc * dc + bias[f];
    float a = pa[0];
    out[(size_t)c * F_OUT + f] = (v >= 0.f) ? v : a * v;
}

// ---------------- Fallback path (old atomic scatter), if ws too small -----
__global__ void k4_scatter(const int* __restrict__ ei, const float* __restrict__ xw,
                           const float* __restrict__ dis, float* __restrict__ out, int E_) {
    int id = blockIdx.x * blockDim.x + threadIdx.x;
    if (id >= E_ * F_OUT) return;
    int e = id >> 5, f = id & 31;
    int r = ei[e];
    int c = ei[E_ + e];
    float nrm = dis[r] * dis[c];
    atomicAdd(&out[(size_t)c * F_OUT + f], xw[(size_t)r * F_OUT + f] * nrm);
}

__global__ void k5_epi(const float* __restrict__ xw, const float* __restrict__ dis,
                       const float* __restrict__ bias, const float* __restrict__ pa,
                       float* __restrict__ out, int Nn) {
    int id = blockIdx.x * blockDim.x + threadIdx.x;
    if (id >= Nn * F_OUT) return;
    int i = id >> 5, f = id & 31;
    float d = dis[i];
    float v = out[id] + xw[id] * d * d + bias[f];
    float a = pa[0];
    out[id] = (v >= 0.f) ? v : a * v;
}

extern "C" void kernel_launch(void* const* d_in, const int* in_sizes, int n_in,
                              void* d_out, int out_size, void* d_ws, size_t ws_size,
                              hipStream_t stream) {
    const float* x    = (const float*)d_in[0];
    const int*   ei   = (const int*)d_in[1];   // [2,E]: row = ei[0:E], col = ei[E:2E]
    const float* W    = (const float*)d_in[2];
    const float* bias = (const float*)d_in[3];
    const float* pa   = (const float*)d_in[4];
    const float* u    = (const float*)d_in[5];

    int Nn = in_sizes[0] / F_IN;   // 100000
    int E_ = in_sizes[1] / 2;      // 1600000
    float* out = (float*)d_out;

    // ws layout (4B words):
    // xw [N*32] | Wsc [4096] | dis [N] | cnt [N] | cursor [N] | bsum [256] | esr [E]
    size_t o = 0;
    float* xw     = (float*)d_ws;            o += (size_t)Nn * F_OUT;
    float* Wsc    = (float*)d_ws + o;        o += F_OUT * F_IN;
    float* dis    = (float*)d_ws + o;        o += Nn;
    int*   cnt    = (int*)d_ws + o;          o += Nn;
    int*   cursor = (int*)d_ws + o;          o += Nn;
    int*   bsum   = (int*)d_ws + o;          o += 256;
    int*   esr    = (int*)d_ws + o;          o += E_;
    bool big_ws = ws_size >= o * sizeof(float);

    hipMemsetAsync(cnt, 0, (size_t)Nn * sizeof(int), stream);

    k0_specnorm<<<1, 128, 0, stream>>>(W, u, Wsc);

    int nb1 = (Nn + 127) / 128;
    k1_xw<<<nb1, 256, 0, stream>>>(x, Wsc, xw, Nn);

    k2_deg<<<(E_ + 255) / 256, 256, 0, stream>>>(ei + E_, cnt, E_);
    k3_dis<<<(Nn + 255) / 256, 256, 0, stream>>>(cnt, dis, Nn);

    if (big_ws) {
        int nbS = (Nn + 1023) / 1024;
        k_s1<<<nbS, 256, 0, stream>>>(cnt, bsum, Nn);
        k_s2<<<1, 64, 0, stream>>>(bsum, nbS);
        k_s3<<<nbS, 256, 0, stream>>>(cnt, bsum, cursor, Nn);
        k_sort<<<(E_ + 255) / 256, 256, 0, stream>>>(ei, cursor, esr, E_);
        k4_gather<<<(Nn + 7) / 8, 256, 0, stream>>>(esr, cursor, cnt, xw, dis,
                                                    bias, pa, out, Nn);
    } else {
        hipMemsetAsync(d_out, 0, (size_t)Nn * F_OUT * sizeof(float), stream);
        int nT4 = E_ * F_OUT;
        k4_scatter<<<(nT4 + 255) / 256, 256, 0, stream>>>(ei, xw, dis, out, E_);
        int nT1 = Nn * F_OUT;
        k5_epi<<<(nT1 + 255) / 256, 256, 0, stream>>>(xw, dis, bias, pa, out, Nn);
    }
}